// Round 3
// baseline (343.097 us; speedup 1.0000x reference)
//
#include <hip/hip_runtime.h>
#include <math.h>

// Problem constants
#define NB 16
#define NF 5
#define NV 4
#define NIMG (NB*NF*NV)          // 320 images
#define IMG_HW 224
#define IMG_CH_STRIDE (224*224)  // 50176
#define H1_HW 37                 // after conv1(s2)+pool3: 111 -> 37
#define H1_CH_STRIDE (37*37)     // 1369
#define H1_IMG 4108              // 3*1369 = 4107, padded to multiple of 4 floats (16B)
#define PB_PER_IMG 13            // 12 blocks x 3 pooled rows + 1 block x 1 row

typedef float v4f __attribute__((ext_vector_type(4)));

// ---------------------------------------------------------------------------
// Kernel 1: conv1 (3->3, k=3, s=2, VALID) + maxpool(3,3) + ReLU, fused.
// One block per (image, 3 pooled rows). Stage 3ch x 19row x 224col band into
// LDS via coalesced nontemporal float4, then 111 threads (3 rows x 37 px),
// each computing ALL 3 out-channels (patch loaded once per ic, reused 3x).
// Last block per image (pb==12) handles pooled row 36 with a 7-row band.
// LDS 51.1 KB -> 3 blocks/CU; issue ~32 us ~= HBM ~33 us (balanced).
// ---------------------------------------------------------------------------
__global__ __launch_bounds__(256) void k1_conv1_pool(
    const float* __restrict__ nodes,   // [320,3,224,224]
    const float* __restrict__ w,       // [3,3,3,3] OIHW
    const float* __restrict__ bias,    // [3]
    float* __restrict__ h1)            // [320, H1_IMG] padded; [3,37,37] inside
{
    const int blk = blockIdx.x;          // img*13 + pb
    const int img = blk / PB_PER_IMG;
    const int pb  = blk - img * PB_PER_IMG;
    const int t   = threadIdx.x;

    const int last   = (pb == PB_PER_IMG - 1);
    const int py0    = 3 * pb;                 // first pooled row of this block
    const int nrows  = last ? 1 : 3;
    const int r0     = 18 * pb;                // first input row staged
    const int nflt   = (6 * nrows + 1) * 224;  // 4256 or 1568 floats per channel
    const int nf4    = nflt >> 2;              // 1064 or 392 float4 per channel

    __shared__ float s[3 * 19 * 224];          // 12768 floats = 51072 B

    // Stage: 3 channel bands, 3 loads in flight per iter, nontemporal
    // (192 MB pure stream; don't evict h1 from L2).
    {
        const v4f* s0 = (const v4f*)(nodes + (size_t)img * 3 * IMG_CH_STRIDE + r0 * IMG_HW);
        const v4f* s1 = s0 + (IMG_CH_STRIDE >> 2);
        const v4f* s2 = s1 + (IMG_CH_STRIDE >> 2);
        v4f* d0 = (v4f*)s;
        v4f* d1 = (v4f*)(s + nflt);
        v4f* d2 = (v4f*)(s + 2 * nflt);
        for (int i = t; i < nf4; i += 256) {
            v4f a0 = __builtin_nontemporal_load(&s0[i]);
            v4f a1 = __builtin_nontemporal_load(&s1[i]);
            v4f a2 = __builtin_nontemporal_load(&s2[i]);
            d0[i] = a0; d1[i] = a1; d2[i] = a2;
        }
    }
    __syncthreads();

    if (t < H1_HW * nrows) {
        const int r  = t / H1_HW;            // pooled row within block (0..2)
        const int px = t - H1_HW * r;

        float acc[3][9];
        #pragma unroll
        for (int oc = 0; oc < 3; ++oc)
            #pragma unroll
            for (int p = 0; p < 9; ++p) acc[oc][p] = 0.f;

        #pragma unroll
        for (int ic = 0; ic < 3; ++ic) {
            // weights: uniform addresses -> scalar-cached
            float wv[3][9];
            #pragma unroll
            for (int oc = 0; oc < 3; ++oc)
                #pragma unroll
                for (int k = 0; k < 9; ++k)
                    wv[oc][k] = w[(oc * 3 + ic) * 9 + k];

            // 7x8 patch from LDS via aligned float2 (6*px even -> 8B aligned),
            // loaded ONCE per ic, reused for all 3 oc.
            float patch[7][8];
            #pragma unroll
            for (int rr = 0; rr < 7; ++rr) {
                const float* row = s + ic * nflt + (6 * r + rr) * 224 + 6 * px;
                #pragma unroll
                for (int k = 0; k < 4; ++k) {
                    float2 q = *(const float2*)(row + 2 * k);
                    patch[rr][2 * k]     = q.x;
                    patch[rr][2 * k + 1] = q.y;
                }
            }

            #pragma unroll
            for (int i = 0; i < 3; ++i)
                #pragma unroll
                for (int j = 0; j < 3; ++j) {
                    const int p = i * 3 + j;
                    #pragma unroll
                    for (int ky = 0; ky < 3; ++ky)
                        #pragma unroll
                        for (int kx = 0; kx < 3; ++kx) {
                            float x = patch[2 * i + ky][2 * j + kx];
                            acc[0][p] += wv[0][ky * 3 + kx] * x;
                            acc[1][p] += wv[1][ky * 3 + kx] * x;
                            acc[2][p] += wv[2][ky * 3 + kx] * x;
                        }
                }
        }

        float* outb = h1 + (size_t)img * H1_IMG + (py0 + r) * H1_HW + px;
        #pragma unroll
        for (int oc = 0; oc < 3; ++oc) {
            float m = -INFINITY;
            #pragma unroll
            for (int p = 0; p < 9; ++p) m = fmaxf(m, acc[oc][p]);
            m += bias[oc];               // max(a)+b == max(a+b)
            m = fmaxf(m, 0.f);
            outb[oc * H1_CH_STRIDE] = m;
        }
    }
}

// ---------------------------------------------------------------------------
// Kernel 2+3 merged: conv2+pool+linear for the 20 images of a batch element
// (5 images per LDS phase x 4 phases; images are contiguous in h1 so each
// stage is one contiguous float4 range), then the graph + readout MLP.
// One block (256 threads) per batch element.
// ---------------------------------------------------------------------------
__global__ __launch_bounds__(256) void k23_feat_graph_mlp(
    const float* __restrict__ h1,      // [320, H1_IMG]
    const float* __restrict__ w2,      // [1,3,3,3]
    const float* __restrict__ b2,      // [1]
    const float* __restrict__ lin_w,   // [36,6]
    const float* __restrict__ lin_b,   // [6]
    const float* __restrict__ pos,     // [NB,NF,NV,6]
    const float* __restrict__ attmap,  // [NB,NF,NV,NV]
    const float* __restrict__ wfc_w,   // [24]
    const float* __restrict__ wfc_b,   // [1]
    const float* __restrict__ fm_w,    // [6,6]
    const float* __restrict__ fm_b,    // [6]
    const float* __restrict__ lm_w,    // [6,6]
    const float* __restrict__ lm_b,    // [6]
    const float* __restrict__ fc1_w,   // [240,120]
    const float* __restrict__ fc1_b,   // [120]
    const float* __restrict__ fc2_w,   // [120,60]
    const float* __restrict__ fc2_b,   // [60]
    const float* __restrict__ fc3_w,   // [60,6]
    const float* __restrict__ fc3_b,   // [6]
    float* __restrict__ out)           // [NB,6]
{
    const int b = blockIdx.x;
    const int t = threadIdx.x;

    __shared__ float s[5 * H1_IMG];      // 20540 floats = 82160 B
    __shared__ float s_h2[5][36];
    __shared__ float s_feat[20][6];

    __shared__ float s_na[NF][NV][12];   // feat || pos
    __shared__ float s_pm[NF][NV][6];
    __shared__ float s_maw[NF][NV][NV];  // [f][src][tgt]
    __shared__ float s_inp[240];
    __shared__ float s_r1[120];
    __shared__ float s_r2[60];

    // ---- per-image CNN tail: conv2(3->1,k3,s2)+pool3+ReLU+linear 36->6 ----
    for (int ph = 0; ph < 4; ++ph) {
        const int img0 = b * 20 + ph * 5;
        // stage 5 contiguous images: 5*1027 float4
        {
            const float4* src = (const float4*)(h1 + (size_t)img0 * H1_IMG);
            float4* d = (float4*)s;
            for (int i = t; i < 5 * 1027; i += 256) d[i] = src[i];
        }
        __syncthreads();

        if (t < 180) {
            const int im = t / 36;
            const int u  = t - im * 36;
            const int py = u / 6, px = u - (u / 6) * 6;
            const float* si = s + im * H1_IMG;
            float m = -INFINITY;
            #pragma unroll
            for (int i = 0; i < 3; ++i)
                #pragma unroll
                for (int j = 0; j < 3; ++j) {
                    const int oy = 3 * py + i, ox = 3 * px + j;
                    float a = 0.f;
                    #pragma unroll
                    for (int ic = 0; ic < 3; ++ic)
                        #pragma unroll
                        for (int ky = 0; ky < 3; ++ky)
                            #pragma unroll
                            for (int kx = 0; kx < 3; ++kx)
                                a += w2[(ic * 3 + ky) * 3 + kx] *
                                     si[ic * H1_CH_STRIDE + (2 * oy + ky) * H1_HW + (2 * ox + kx)];
                    m = fmaxf(m, a);
                }
            m += b2[0];
            s_h2[im][u] = fmaxf(m, 0.f);
        }
        __syncthreads();

        if (t < 30) {
            const int im = t / 6, d = t - (t / 6) * 6;
            float a = lin_b[d];
            #pragma unroll
            for (int i = 0; i < 36; ++i) a += s_h2[im][i] * lin_w[i * 6 + d];
            s_feat[ph * 5 + im][d] = a;
        }
        __syncthreads();   // also orders s_h2/s reuse for the next phase
    }

    // ---- graph section ----
    if (t < 120) {
        int f = t / 24;
        int v = (t / 6) % 4;
        int d = t % 6;
        float fv = s_feat[f * NV + v][d];
        float pv = pos[((b * NF + f) * NV + v) * 6 + d];
        s_na[f][v][d]     = fv;
        s_na[f][v][6 + d] = pv;
        s_inp[(f * NV + v) * 12 + d] = fv;
    }
    __syncthreads();

    if (t < 120) {
        int f = t / 24;
        int v = (t / 6) % 4;
        int d = t % 6;
        float a = fm_b[d];
        #pragma unroll
        for (int k = 0; k < 6; ++k) a += s_na[f][v][6 + k] * fm_w[k * 6 + d];
        s_pm[f][v][d] = a;
    }
    if (t < 80) {
        int f = t / 16;
        int sidx = (t / 4) % 4;
        int tt = t % 4;
        float x = wfc_b[0];
        #pragma unroll
        for (int k = 0; k < 12; ++k)
            x += wfc_w[k] * s_na[f][sidx][k] + wfc_w[12 + k] * s_na[f][tt][k];
        float sig = 1.f / (1.f + expf(-x));
        s_maw[f][sidx][tt] = sig + attmap[((b * NF + f) * NV + sidx) * NV + tt];
    }
    __syncthreads();

    if (t < 120) {
        int f = t / 24;
        int n = (t / 6) % 4;
        int d = t % 6;
        float a = 0.f;
        #pragma unroll
        for (int sidx = 0; sidx < 4; ++sidx) a += s_maw[f][sidx][n] * s_pm[f][sidx][d];
        if (f > 0) {
            float l = lm_b[d];
            #pragma unroll
            for (int k = 0; k < 6; ++k) l += s_na[f - 1][n][6 + k] * lm_w[k * 6 + d];
            a += l;
        }
        s_inp[(f * NV + n) * 12 + 6 + d] = a;
    }
    __syncthreads();

    if (t < 120) {
        float a = fc1_b[t];
        #pragma unroll 16
        for (int i = 0; i < 240; ++i) a += s_inp[i] * fc1_w[i * 120 + t];
        s_r1[t] = fmaxf(a, 0.f);
    }
    __syncthreads();

    if (t < 60) {
        float a = fc2_b[t];
        #pragma unroll 16
        for (int i = 0; i < 120; ++i) a += s_r1[i] * fc2_w[i * 60 + t];
        s_r2[t] = fmaxf(a, 0.f);
    }
    __syncthreads();

    if (t < 6) {
        float a = fc3_b[t];
        #pragma unroll 12
        for (int i = 0; i < 60; ++i) a += s_r2[i] * fc3_w[i * 6 + t];
        out[b * 6 + t] = a;
    }
}

// ---------------------------------------------------------------------------
extern "C" void kernel_launch(void* const* d_in, const int* in_sizes, int n_in,
                              void* d_out, int out_size, void* d_ws, size_t ws_size,
                              hipStream_t stream) {
    const float* nodes   = (const float*)d_in[0];
    const float* pos     = (const float*)d_in[1];
    const float* attmap  = (const float*)d_in[2];
    // d_in[3] = depths : unused by the reference
    const float* conv1_w = (const float*)d_in[4];
    const float* conv1_b = (const float*)d_in[5];
    const float* conv2_w = (const float*)d_in[6];
    const float* conv2_b = (const float*)d_in[7];
    const float* lin_w   = (const float*)d_in[8];
    const float* lin_b   = (const float*)d_in[9];
    const float* wfc_w   = (const float*)d_in[10];
    const float* wfc_b   = (const float*)d_in[11];
    const float* fm_w    = (const float*)d_in[12];
    const float* fm_b    = (const float*)d_in[13];
    const float* lm_w    = (const float*)d_in[14];
    const float* lm_b    = (const float*)d_in[15];
    const float* fc1_w   = (const float*)d_in[16];
    const float* fc1_b   = (const float*)d_in[17];
    const float* fc2_w   = (const float*)d_in[18];
    const float* fc2_b   = (const float*)d_in[19];
    const float* fc3_w   = (const float*)d_in[20];
    const float* fc3_b   = (const float*)d_in[21];

    float* h1 = (float*)d_ws;                              // 320 * 4108 floats

    k1_conv1_pool<<<NIMG * PB_PER_IMG, 256, 0, stream>>>(nodes, conv1_w, conv1_b, h1);
    k23_feat_graph_mlp<<<NB, 256, 0, stream>>>(h1, conv2_w, conv2_b, lin_w, lin_b,
                                               pos, attmap,
                                               wfc_w, wfc_b, fm_w, fm_b, lm_w, lm_b,
                                               fc1_w, fc1_b, fc2_w, fc2_b, fc3_w, fc3_b,
                                               (float*)d_out);
}

// Round 4
// 329.616 us; speedup vs baseline: 1.0409x; 1.0409x over previous
//
#include <hip/hip_runtime.h>
#include <math.h>

// Problem constants
#define NB 16
#define NF 5
#define NV 4
#define NIMG (NB*NF*NV)          // 320 images
#define IMG_HW 224
#define IMG_CH_STRIDE (224*224)  // 50176
#define H1_HW 37                 // after conv1(s2)+pool3: 111 -> 37
#define H1_CH_STRIDE (37*37)     // 1369
#define H1_IMG 4108              // 3*1369 = 4107, padded to multiple of 4 floats (16B)
#define PB_PER_IMG 13            // 12 blocks x 3 pooled rows + 1 block x 1 row

// ---------------------------------------------------------------------------
// Kernel 1: conv1 (3->3, k=3, s=2, VALID) + maxpool(3,3) + ReLU, fused.
// One block per (image, 3 pooled rows). Stage 3ch x 19row x 224col band into
// LDS via global_load_lds width=16 (no VGPR roundtrip, no ds_writes), then
// 111 threads (3 rows x 37 px), each computing ALL 3 out-channels (patch
// loaded once per ic, reused 3x -> minimum LDS-read traffic).
// Last block per image (pb==12) handles pooled row 36 with a 7-row band.
// Per-CU pipe model: FMA ~5 us, LDS-read ~8 us, HBM ~32 us -> HBM-bound.
// ---------------------------------------------------------------------------
__global__ __launch_bounds__(256) void k1_conv1_pool(
    const float* __restrict__ nodes,   // [320,3,224,224]
    const float* __restrict__ w,       // [3,3,3,3] OIHW
    const float* __restrict__ bias,    // [3]
    float* __restrict__ h1)            // [320, H1_IMG] padded; [3,37,37] inside
{
    const int blk = blockIdx.x;          // img*13 + pb
    const int img = blk / PB_PER_IMG;
    const int pb  = blk - img * PB_PER_IMG;
    const int t   = threadIdx.x;

    const int last   = (pb == PB_PER_IMG - 1);
    const int py0    = 3 * pb;                 // first pooled row of this block
    const int nrows  = last ? 1 : 3;
    const int r0     = 18 * pb;                // first input row staged
    const int nflt   = (6 * nrows + 1) * 224;  // 4256 or 1568 floats per channel
    const int nf4    = nflt >> 2;              // 1064 or 392 float4 per channel

    __shared__ float s[3 * 19 * 224];          // 12768 floats = 51072 B

    // Stage: 3 channel bands via async global->LDS (16B per lane, contiguous
    // per-wave so the wave-uniform-base + lane*16 LDS write pattern holds).
    {
        const float* g0 = nodes + (size_t)img * 3 * IMG_CH_STRIDE + r0 * IMG_HW;
        const float* g1 = g0 + IMG_CH_STRIDE;
        const float* g2 = g0 + 2 * IMG_CH_STRIDE;
        for (int i = t; i < nf4; i += 256) {
            const int o = 4 * i;
            __builtin_amdgcn_global_load_lds(
                (const __attribute__((address_space(1))) unsigned int*)(g0 + o),
                (__attribute__((address_space(3))) unsigned int*)(s + o), 16, 0, 0);
            __builtin_amdgcn_global_load_lds(
                (const __attribute__((address_space(1))) unsigned int*)(g1 + o),
                (__attribute__((address_space(3))) unsigned int*)(s + nflt + o), 16, 0, 0);
            __builtin_amdgcn_global_load_lds(
                (const __attribute__((address_space(1))) unsigned int*)(g2 + o),
                (__attribute__((address_space(3))) unsigned int*)(s + 2 * nflt + o), 16, 0, 0);
        }
    }
    __syncthreads();   // compiler emits s_waitcnt vmcnt(0) before s_barrier

    if (t < H1_HW * nrows) {
        const int r  = t / H1_HW;            // pooled row within block (0..2)
        const int px = t - H1_HW * r;

        float acc[3][9];
        #pragma unroll
        for (int oc = 0; oc < 3; ++oc)
            #pragma unroll
            for (int p = 0; p < 9; ++p) acc[oc][p] = 0.f;

        #pragma unroll
        for (int ic = 0; ic < 3; ++ic) {
            // weights: uniform compile-time-indexed addresses -> scalar-cached
            float wv[3][9];
            #pragma unroll
            for (int oc = 0; oc < 3; ++oc)
                #pragma unroll
                for (int k = 0; k < 9; ++k)
                    wv[oc][k] = w[(oc * 3 + ic) * 9 + k];

            // 7x8 patch from LDS via aligned float2 (6*px even -> 8B aligned),
            // loaded ONCE per ic, reused for all 3 oc.
            float patch[7][8];
            #pragma unroll
            for (int rr = 0; rr < 7; ++rr) {
                const float* row = s + ic * nflt + (6 * r + rr) * 224 + 6 * px;
                #pragma unroll
                for (int k = 0; k < 4; ++k) {
                    float2 q = *(const float2*)(row + 2 * k);
                    patch[rr][2 * k]     = q.x;
                    patch[rr][2 * k + 1] = q.y;
                }
            }

            #pragma unroll
            for (int i = 0; i < 3; ++i)
                #pragma unroll
                for (int j = 0; j < 3; ++j) {
                    const int p = i * 3 + j;
                    #pragma unroll
                    for (int ky = 0; ky < 3; ++ky)
                        #pragma unroll
                        for (int kx = 0; kx < 3; ++kx) {
                            float x = patch[2 * i + ky][2 * j + kx];
                            acc[0][p] += wv[0][ky * 3 + kx] * x;
                            acc[1][p] += wv[1][ky * 3 + kx] * x;
                            acc[2][p] += wv[2][ky * 3 + kx] * x;
                        }
                }
        }

        float* outb = h1 + (size_t)img * H1_IMG + (py0 + r) * H1_HW + px;
        #pragma unroll
        for (int oc = 0; oc < 3; ++oc) {
            float m = -INFINITY;
            #pragma unroll
            for (int p = 0; p < 9; ++p) m = fmaxf(m, acc[oc][p]);
            m += bias[oc];               // max(a)+b == max(a+b)
            m = fmaxf(m, 0.f);
            outb[oc * H1_CH_STRIDE] = m;
        }
    }
}

// ---------------------------------------------------------------------------
// Kernel 2: conv2 (3->1, k=3, s=2) + maxpool(3,3) + ReLU + linear 36->6.
// One block (128 threads) per image; h1 image staged to LDS via float4.
// 320 blocks -> full-chip parallelism (the R3 16-block merge regressed).
// ---------------------------------------------------------------------------
__global__ __launch_bounds__(128) void k2_conv2_pool_lin(
    const float* __restrict__ h1,     // [320, H1_IMG]
    const float* __restrict__ w2,     // [1,3,3,3]
    const float* __restrict__ b2,     // [1]
    const float* __restrict__ lin_w,  // [36,6]
    const float* __restrict__ lin_b,  // [6]
    float* __restrict__ feat)         // [320,6]
{
    const int img = blockIdx.x;
    const int t   = threadIdx.x;
    __shared__ float s[H1_IMG];       // 4108 floats (last one is pad, unused)
    __shared__ float s_h2[36];

    // Stage 1027 float4 (= 4108 floats) with 128 threads: 8 full + 1 partial.
    {
        const float4* src = (const float4*)(h1 + (size_t)img * H1_IMG);
        float4* d = (float4*)s;
        float4 v[8];
        #pragma unroll
        for (int k = 0; k < 8; ++k) v[k] = src[t + 128 * k];   // max 127+896=1023 < 1027
        const bool hi = (t < 1027 - 1024);                      // t < 3
        float4 v8;
        if (hi) v8 = src[t + 1024];
        #pragma unroll
        for (int k = 0; k < 8; ++k) d[t + 128 * k] = v[k];
        if (hi) d[t + 1024] = v8;
    }
    __syncthreads();

    if (t < 36) {
        const int py = t / 6, px = t - (t / 6) * 6;
        float m = -INFINITY;
        #pragma unroll
        for (int i = 0; i < 3; ++i)
            #pragma unroll
            for (int j = 0; j < 3; ++j) {
                const int oy = 3 * py + i, ox = 3 * px + j;
                float a = 0.f;
                #pragma unroll
                for (int ic = 0; ic < 3; ++ic)
                    #pragma unroll
                    for (int ky = 0; ky < 3; ++ky)
                        #pragma unroll
                        for (int kx = 0; kx < 3; ++kx)
                            a += w2[(ic * 3 + ky) * 3 + kx] *
                                 s[ic * H1_CH_STRIDE + (2 * oy + ky) * H1_HW + (2 * ox + kx)];
                m = fmaxf(m, a);
            }
        m += b2[0];
        s_h2[t] = fmaxf(m, 0.f);
    }
    __syncthreads();
    if (t < 6) {
        float a = lin_b[t];
        #pragma unroll
        for (int i = 0; i < 36; ++i) a += s_h2[i] * lin_w[i * 6 + t];
        feat[img * 6 + t] = a;
    }
}

// ---------------------------------------------------------------------------
// Kernel 3: edge weights + attention aggregation + last-frame message +
// readout MLP. One block (128 threads) per batch element.
// ---------------------------------------------------------------------------
__global__ __launch_bounds__(128) void k3_graph_mlp(
    const float* __restrict__ feat,    // [320,6] = [NB,NF,NV,6]
    const float* __restrict__ pos,     // [NB,NF,NV,6]
    const float* __restrict__ attmap,  // [NB,NF,NV,NV]
    const float* __restrict__ wfc_w,   // [24]
    const float* __restrict__ wfc_b,   // [1]
    const float* __restrict__ fm_w,    // [6,6]
    const float* __restrict__ fm_b,    // [6]
    const float* __restrict__ lm_w,    // [6,6]
    const float* __restrict__ lm_b,    // [6]
    const float* __restrict__ fc1_w,   // [240,120]
    const float* __restrict__ fc1_b,   // [120]
    const float* __restrict__ fc2_w,   // [120,60]
    const float* __restrict__ fc2_b,   // [60]
    const float* __restrict__ fc3_w,   // [60,6]
    const float* __restrict__ fc3_b,   // [6]
    float* __restrict__ out)           // [NB,6]
{
    const int b = blockIdx.x;
    const int t = threadIdx.x;

    __shared__ float s_na[NF][NV][12];   // feat || pos
    __shared__ float s_pm[NF][NV][6];
    __shared__ float s_maw[NF][NV][NV];  // [f][s][t]
    __shared__ float s_inp[240];
    __shared__ float s_r1[120];
    __shared__ float s_r2[60];

    if (t < 120) {
        int f = t / 24;
        int v = (t / 6) % 4;
        int d = t % 6;
        float fv = feat[((b * NF + f) * NV + v) * 6 + d];
        float pv = pos[((b * NF + f) * NV + v) * 6 + d];
        s_na[f][v][d]     = fv;
        s_na[f][v][6 + d] = pv;
        s_inp[(f * NV + v) * 12 + d] = fv;
    }
    __syncthreads();

    if (t < 120) {
        int f = t / 24;
        int v = (t / 6) % 4;
        int d = t % 6;
        float a = fm_b[d];
        #pragma unroll
        for (int k = 0; k < 6; ++k) a += s_na[f][v][6 + k] * fm_w[k * 6 + d];
        s_pm[f][v][d] = a;
    }
    if (t < 80) {
        int f = t / 16;
        int sidx = (t / 4) % 4;
        int tt = t % 4;
        float x = wfc_b[0];
        #pragma unroll
        for (int k = 0; k < 12; ++k)
            x += wfc_w[k] * s_na[f][sidx][k] + wfc_w[12 + k] * s_na[f][tt][k];
        float sig = 1.f / (1.f + expf(-x));
        s_maw[f][sidx][tt] = sig + attmap[((b * NF + f) * NV + sidx) * NV + tt];
    }
    __syncthreads();

    if (t < 120) {
        int f = t / 24;
        int n = (t / 6) % 4;
        int d = t % 6;
        float a = 0.f;
        #pragma unroll
        for (int sidx = 0; sidx < 4; ++sidx) a += s_maw[f][sidx][n] * s_pm[f][sidx][d];
        if (f > 0) {
            float l = lm_b[d];
            #pragma unroll
            for (int k = 0; k < 6; ++k) l += s_na[f - 1][n][6 + k] * lm_w[k * 6 + d];
            a += l;
        }
        s_inp[(f * NV + n) * 12 + 6 + d] = a;
    }
    __syncthreads();

    if (t < 120) {
        float a = fc1_b[t];
        #pragma unroll 16
        for (int i = 0; i < 240; ++i) a += s_inp[i] * fc1_w[i * 120 + t];
        s_r1[t] = fmaxf(a, 0.f);
    }
    __syncthreads();

    if (t < 60) {
        float a = fc2_b[t];
        #pragma unroll 16
        for (int i = 0; i < 120; ++i) a += s_r1[i] * fc2_w[i * 60 + t];
        s_r2[t] = fmaxf(a, 0.f);
    }
    __syncthreads();

    if (t < 6) {
        float a = fc3_b[t];
        #pragma unroll 12
        for (int i = 0; i < 60; ++i) a += s_r2[i] * fc3_w[i * 6 + t];
        out[b * 6 + t] = a;
    }
}

// ---------------------------------------------------------------------------
extern "C" void kernel_launch(void* const* d_in, const int* in_sizes, int n_in,
                              void* d_out, int out_size, void* d_ws, size_t ws_size,
                              hipStream_t stream) {
    const float* nodes   = (const float*)d_in[0];
    const float* pos     = (const float*)d_in[1];
    const float* attmap  = (const float*)d_in[2];
    // d_in[3] = depths : unused by the reference
    const float* conv1_w = (const float*)d_in[4];
    const float* conv1_b = (const float*)d_in[5];
    const float* conv2_w = (const float*)d_in[6];
    const float* conv2_b = (const float*)d_in[7];
    const float* lin_w   = (const float*)d_in[8];
    const float* lin_b   = (const float*)d_in[9];
    const float* wfc_w   = (const float*)d_in[10];
    const float* wfc_b   = (const float*)d_in[11];
    const float* fm_w    = (const float*)d_in[12];
    const float* fm_b    = (const float*)d_in[13];
    const float* lm_w    = (const float*)d_in[14];
    const float* lm_b    = (const float*)d_in[15];
    const float* fc1_w   = (const float*)d_in[16];
    const float* fc1_b   = (const float*)d_in[17];
    const float* fc2_w   = (const float*)d_in[18];
    const float* fc2_b   = (const float*)d_in[19];
    const float* fc3_w   = (const float*)d_in[20];
    const float* fc3_b   = (const float*)d_in[21];

    float* h1      = (float*)d_ws;                         // 320 * 4108 floats
    float* feat_ws = h1 + (size_t)NIMG * H1_IMG;           // 320*6 floats

    k1_conv1_pool<<<NIMG * PB_PER_IMG, 256, 0, stream>>>(nodes, conv1_w, conv1_b, h1);
    k2_conv2_pool_lin<<<NIMG, 128, 0, stream>>>(h1, conv2_w, conv2_b, lin_w, lin_b, feat_ws);
    k3_graph_mlp<<<NB, 128, 0, stream>>>(feat_ws, pos, attmap,
                                         wfc_w, wfc_b, fm_w, fm_b, lm_w, lm_b,
                                         fc1_w, fc1_b, fc2_w, fc2_b, fc3_w, fc3_b,
                                         (float*)d_out);
}

// Round 5
// 320.905 us; speedup vs baseline: 1.0692x; 1.0271x over previous
//
#include <hip/hip_runtime.h>
#include <math.h>

// Problem constants
#define NB 16
#define NF 5
#define NV 4
#define NIMG (NB*NF*NV)          // 320 images
#define IMG_HW 224
#define IMG_CH_STRIDE (224*224)  // 50176
#define H1_HW 37                 // after conv1(s2)+pool3: 111 -> 37
#define H1_CH_STRIDE (37*37)     // 1369
#define H1_IMG 4108              // 3*1369 = 4107, padded to multiple of 4 floats (16B)
#define PB_PER_IMG 19            // ceil(37/2) pooled-row pairs per image

typedef float v4f __attribute__((ext_vector_type(4)));

// ---------------------------------------------------------------------------
// Kernel 1: conv1 (3->3, k=3, s=2, VALID) + maxpool(3,3) + ReLU, fused.
// One block per (image, pooled-row PAIR). Stage 3ch x 13row x 224col band into
// LDS via coalesced nontemporal float4, then 222 threads (2 rows x 3 oc x
// 37 px) compute from LDS. Last block (pb==18) handles the single leftover
// pooled row with a 7-row band. 35 KB LDS -> 4 blocks/CU residency.
// Best-measured configuration (321.5 us total).
// ---------------------------------------------------------------------------
__global__ __launch_bounds__(256) void k1_conv1_pool(
    const float* __restrict__ nodes,   // [320,3,224,224]
    const float* __restrict__ w,       // [3,3,3,3] OIHW
    const float* __restrict__ bias,    // [3]
    float* __restrict__ h1)            // [320, H1_IMG] padded; [3,37,37] inside
{
    const int blk = blockIdx.x;          // img*19 + pb
    const int img = blk / PB_PER_IMG;
    const int pb  = blk - img * PB_PER_IMG;
    const int t   = threadIdx.x;

    const int py0    = 2 * pb;                 // first pooled row of this block
    const int nrows  = (pb == PB_PER_IMG - 1) ? 1 : 2;
    const int r0     = 12 * pb;                // first input row staged
    const int nflt   = (6 * nrows + 1) * 224;  // 2912 or 1568 floats per channel
    const int nf4    = nflt >> 2;              // 728 or 392 float4 per channel

    __shared__ float s[3 * 13 * 224];          // 8736 floats = 34944 B
    __shared__ float s_w[27 * 3];              // conv1 weights [oc][ic][ky][kx]
    __shared__ float s_b[3];

    if (t < 81) s_w[t] = w[t];
    if (t < 3)  s_b[t] = bias[t];

    // Stage: 3 channel bands, 3 loads in flight per iter, nontemporal
    // (192 MB pure stream; don't evict h1 from L2).
    {
        const v4f* s0 = (const v4f*)(nodes + (size_t)img * 3 * IMG_CH_STRIDE + r0 * IMG_HW);
        const v4f* s1 = s0 + (IMG_CH_STRIDE >> 2);
        const v4f* s2 = s1 + (IMG_CH_STRIDE >> 2);
        v4f* d0 = (v4f*)s;
        v4f* d1 = (v4f*)(s + nflt);
        v4f* d2 = (v4f*)(s + 2 * nflt);
        for (int i = t; i < nf4; i += 256) {
            v4f a0 = __builtin_nontemporal_load(&s0[i]);
            v4f a1 = __builtin_nontemporal_load(&s1[i]);
            v4f a2 = __builtin_nontemporal_load(&s2[i]);
            d0[i] = a0; d1[i] = a1; d2[i] = a2;
        }
    }
    __syncthreads();

    if (t < 111 * nrows) {
        const int r  = (t >= 111) ? 1 : 0;   // pooled row within pair
        const int u  = t - 111 * r;
        const int oc = u / 37;
        const int px = u - 37 * oc;

        float acc[9];
        #pragma unroll
        for (int p = 0; p < 9; ++p) acc[p] = 0.f;

        #pragma unroll
        for (int ic = 0; ic < 3; ++ic) {
            float wv[9];
            #pragma unroll
            for (int k = 0; k < 9; ++k) wv[k] = s_w[(oc * 3 + ic) * 9 + k];

            // 7x8 patch from LDS via aligned float2 (6*px is even -> 8B aligned).
            float patch[7][8];
            #pragma unroll
            for (int rr = 0; rr < 7; ++rr) {
                const float* row = s + ic * nflt + (6 * r + rr) * 224 + 6 * px;
                #pragma unroll
                for (int k = 0; k < 4; ++k) {
                    float2 q = *(const float2*)(row + 2 * k);
                    patch[rr][2 * k]     = q.x;
                    patch[rr][2 * k + 1] = q.y;
                }
            }

            #pragma unroll
            for (int i = 0; i < 3; ++i)
                #pragma unroll
                for (int j = 0; j < 3; ++j) {
                    const int p = i * 3 + j;
                    #pragma unroll
                    for (int ky = 0; ky < 3; ++ky)
                        #pragma unroll
                        for (int kx = 0; kx < 3; ++kx)
                            acc[p] += wv[ky * 3 + kx] * patch[2 * i + ky][2 * j + kx];
                }
        }

        float m = -INFINITY;
        #pragma unroll
        for (int p = 0; p < 9; ++p) m = fmaxf(m, acc[p]);
        m += s_b[oc];                 // max(a)+b == max(a+b)
        m = fmaxf(m, 0.f);
        h1[(size_t)img * H1_IMG + oc * H1_CH_STRIDE + (py0 + r) * H1_HW + px] = m;
    }
}

// ---------------------------------------------------------------------------
// Kernel 2: conv2 (3->1, k=3, s=2) + maxpool(3,3) + ReLU + linear 36->6.
// One block (128 threads) per image; h1 image staged to LDS via float4.
// ---------------------------------------------------------------------------
__global__ __launch_bounds__(128) void k2_conv2_pool_lin(
    const float* __restrict__ h1,     // [320, H1_IMG]
    const float* __restrict__ w2,     // [1,3,3,3]
    const float* __restrict__ b2,     // [1]
    const float* __restrict__ lin_w,  // [36,6]
    const float* __restrict__ lin_b,  // [6]
    float* __restrict__ feat)         // [320,6]
{
    const int img = blockIdx.x;
    const int t   = threadIdx.x;
    __shared__ float s[H1_IMG];       // 4108 floats (last one is pad, unused)
    __shared__ float s_h2[36];

    // Stage 1027 float4 (= 4108 floats) with 128 threads: 8 full + 1 partial.
    {
        const float4* src = (const float4*)(h1 + (size_t)img * H1_IMG);
        float4* d = (float4*)s;
        float4 v[8];
        #pragma unroll
        for (int k = 0; k < 8; ++k) v[k] = src[t + 128 * k];   // max 127+896=1023 < 1027
        const bool hi = (t < 1027 - 1024);                      // t < 3
        float4 v8;
        if (hi) v8 = src[t + 1024];
        #pragma unroll
        for (int k = 0; k < 8; ++k) d[t + 128 * k] = v[k];
        if (hi) d[t + 1024] = v8;
    }
    __syncthreads();

    if (t < 36) {
        const int py = t / 6, px = t - (t / 6) * 6;
        float m = -INFINITY;
        #pragma unroll
        for (int i = 0; i < 3; ++i)
            #pragma unroll
            for (int j = 0; j < 3; ++j) {
                const int oy = 3 * py + i, ox = 3 * px + j;
                float a = 0.f;
                #pragma unroll
                for (int ic = 0; ic < 3; ++ic)
                    #pragma unroll
                    for (int ky = 0; ky < 3; ++ky)
                        #pragma unroll
                        for (int kx = 0; kx < 3; ++kx)
                            a += w2[(ic * 3 + ky) * 3 + kx] *
                                 s[ic * H1_CH_STRIDE + (2 * oy + ky) * H1_HW + (2 * ox + kx)];
                m = fmaxf(m, a);
            }
        m += b2[0];
        s_h2[t] = fmaxf(m, 0.f);
    }
    __syncthreads();
    if (t < 6) {
        float a = lin_b[t];
        #pragma unroll
        for (int i = 0; i < 36; ++i) a += s_h2[i] * lin_w[i * 6 + t];
        feat[img * 6 + t] = a;
    }
}

// ---------------------------------------------------------------------------
// Kernel 3: edge weights + attention aggregation + last-frame message +
// readout MLP. One block (128 threads) per batch element.
// ---------------------------------------------------------------------------
__global__ __launch_bounds__(128) void k3_graph_mlp(
    const float* __restrict__ feat,    // [320,6] = [NB,NF,NV,6]
    const float* __restrict__ pos,     // [NB,NF,NV,6]
    const float* __restrict__ attmap,  // [NB,NF,NV,NV]
    const float* __restrict__ wfc_w,   // [24]
    const float* __restrict__ wfc_b,   // [1]
    const float* __restrict__ fm_w,    // [6,6]
    const float* __restrict__ fm_b,    // [6]
    const float* __restrict__ lm_w,    // [6,6]
    const float* __restrict__ lm_b,    // [6]
    const float* __restrict__ fc1_w,   // [240,120]
    const float* __restrict__ fc1_b,   // [120]
    const float* __restrict__ fc2_w,   // [120,60]
    const float* __restrict__ fc2_b,   // [60]
    const float* __restrict__ fc3_w,   // [60,6]
    const float* __restrict__ fc3_b,   // [6]
    float* __restrict__ out)           // [NB,6]
{
    const int b = blockIdx.x;
    const int t = threadIdx.x;

    __shared__ float s_na[NF][NV][12];   // feat || pos
    __shared__ float s_pm[NF][NV][6];
    __shared__ float s_maw[NF][NV][NV];  // [f][s][t]
    __shared__ float s_inp[240];
    __shared__ float s_r1[120];
    __shared__ float s_r2[60];

    if (t < 120) {
        int f = t / 24;
        int v = (t / 6) % 4;
        int d = t % 6;
        float fv = feat[((b * NF + f) * NV + v) * 6 + d];
        float pv = pos[((b * NF + f) * NV + v) * 6 + d];
        s_na[f][v][d]     = fv;
        s_na[f][v][6 + d] = pv;
        s_inp[(f * NV + v) * 12 + d] = fv;
    }
    __syncthreads();

    if (t < 120) {
        int f = t / 24;
        int v = (t / 6) % 4;
        int d = t % 6;
        float a = fm_b[d];
        #pragma unroll
        for (int k = 0; k < 6; ++k) a += s_na[f][v][6 + k] * fm_w[k * 6 + d];
        s_pm[f][v][d] = a;
    }
    if (t < 80) {
        int f = t / 16;
        int sidx = (t / 4) % 4;
        int tt = t % 4;
        float x = wfc_b[0];
        #pragma unroll
        for (int k = 0; k < 12; ++k)
            x += wfc_w[k] * s_na[f][sidx][k] + wfc_w[12 + k] * s_na[f][tt][k];
        float sig = 1.f / (1.f + expf(-x));
        s_maw[f][sidx][tt] = sig + attmap[((b * NF + f) * NV + sidx) * NV + tt];
    }
    __syncthreads();

    if (t < 120) {
        int f = t / 24;
        int n = (t / 6) % 4;
        int d = t % 6;
        float a = 0.f;
        #pragma unroll
        for (int sidx = 0; sidx < 4; ++sidx) a += s_maw[f][sidx][n] * s_pm[f][sidx][d];
        if (f > 0) {
            float l = lm_b[d];
            #pragma unroll
            for (int k = 0; k < 6; ++k) l += s_na[f - 1][n][6 + k] * lm_w[k * 6 + d];
            a += l;
        }
        s_inp[(f * NV + n) * 12 + 6 + d] = a;
    }
    __syncthreads();

    if (t < 120) {
        float a = fc1_b[t];
        #pragma unroll 16
        for (int i = 0; i < 240; ++i) a += s_inp[i] * fc1_w[i * 120 + t];
        s_r1[t] = fmaxf(a, 0.f);
    }
    __syncthreads();

    if (t < 60) {
        float a = fc2_b[t];
        #pragma unroll 16
        for (int i = 0; i < 120; ++i) a += s_r1[i] * fc2_w[i * 60 + t];
        s_r2[t] = fmaxf(a, 0.f);
    }
    __syncthreads();

    if (t < 6) {
        float a = fc3_b[t];
        #pragma unroll 12
        for (int i = 0; i < 60; ++i) a += s_r2[i] * fc3_w[i * 6 + t];
        out[b * 6 + t] = a;
    }
}

// ---------------------------------------------------------------------------
extern "C" void kernel_launch(void* const* d_in, const int* in_sizes, int n_in,
                              void* d_out, int out_size, void* d_ws, size_t ws_size,
                              hipStream_t stream) {
    const float* nodes   = (const float*)d_in[0];
    const float* pos     = (const float*)d_in[1];
    const float* attmap  = (const float*)d_in[2];
    // d_in[3] = depths : unused by the reference
    const float* conv1_w = (const float*)d_in[4];
    const float* conv1_b = (const float*)d_in[5];
    const float* conv2_w = (const float*)d_in[6];
    const float* conv2_b = (const float*)d_in[7];
    const float* lin_w   = (const float*)d_in[8];
    const float* lin_b   = (const float*)d_in[9];
    const float* wfc_w   = (const float*)d_in[10];
    const float* wfc_b   = (const float*)d_in[11];
    const float* fm_w    = (const float*)d_in[12];
    const float* fm_b    = (const float*)d_in[13];
    const float* lm_w    = (const float*)d_in[14];
    const float* lm_b    = (const float*)d_in[15];
    const float* fc1_w   = (const float*)d_in[16];
    const float* fc1_b   = (const float*)d_in[17];
    const float* fc2_w   = (const float*)d_in[18];
    const float* fc2_b   = (const float*)d_in[19];
    const float* fc3_w   = (const float*)d_in[20];
    const float* fc3_b   = (const float*)d_in[21];

    float* h1      = (float*)d_ws;                         // 320 * 4108 floats
    float* feat_ws = h1 + (size_t)NIMG * H1_IMG;           // 320*6 floats

    k1_conv1_pool<<<NIMG * PB_PER_IMG, 256, 0, stream>>>(nodes, conv1_w, conv1_b, h1);
    k2_conv2_pool_lin<<<NIMG, 128, 0, stream>>>(h1, conv2_w, conv2_b, lin_w, lin_b, feat_ws);
    k3_graph_mlp<<<NB, 128, 0, stream>>>(feat_ws, pos, attmap,
                                         wfc_w, wfc_b, fm_w, fm_b, lm_w, lm_b,
                                         fc1_w, fc1_b, fc2_w, fc2_b, fc3_w, fc3_b,
                                         (float*)d_out);
}